// Round 7
// baseline (801.202 us; speedup 1.0000x reference)
//
#include <hip/hip_runtime.h>
#include <hip/hip_bf16.h>
#include <math.h>

constexpr int NN  = 16384;
constexpr int DD  = 64;
constexpr int CC  = 128;
constexpr int OO  = 128;
constexpr int KP1 = 17;
constexpr int NT  = 256;             // 64-col tiles per row
constexpr int CAP = 256;             // candidate cap per row

typedef __attribute__((ext_vector_type(8))) short short8;
typedef __attribute__((ext_vector_type(4))) float floatx4;

__device__ __forceinline__ float bf2f(unsigned short u) {
    union { unsigned u; float f; } c; c.u = ((unsigned)u) << 16; return c.f;
}
__device__ __forceinline__ unsigned short f2bf(float f) {
    union { float f; unsigned u; } c; c.f = f;
    unsigned b = c.u;
    return (unsigned short)((b + 0x7FFFu + ((b >> 16) & 1u)) >> 16);
}

// ---------------------------------------------------------------------------
// znbF: fragment-major bf16 layout. For node n, channel c:
//   tile t = n>>4, lm = n&15, kt = c>>5, lk = (c>>3)&3, e = c&7, lane = lk*16+lm
//   znbF[ ((t*4 + kt)*64 + lane)*8 + e ]
//
// GEMM structure notes (rounds 1-5 post-mortems, MI355X):
//  - LDS staging (any depth) and all-upfront loads both LOSE to the simple
//    interleaved direct-load schedule below (latency-bound ~13% MfmaUtil but
//    empirically the best schedule for this skinny-K GEMM). Keep it.
//  - XCD swizzle: 14x FETCH blowup. Natural dispatch order only.
//  - Symmetry sim = zn.zn^T: upper-triangle grid (8256 blocks), each block's
//    accumulators serve BOTH (row,col) and (col,row); bit-identical fp32
//    (same products, same k-order, fixed HW reduction tree). Verified R6:
//    895 -> 793 us, absmax unchanged.
//  - R6 tail fusion: gather+layer fused (x2), head fused into layer2;
//    meanb/h2 intermediates eliminated. Identical summation order.
// ---------------------------------------------------------------------------

// Triangular decode: bid -> (i,j), 0 <= i <= j < 128 (i fastest within j).
__device__ __forceinline__ void tri_coords(int bid, int& i, int& j) {
    j = (int)((sqrt(8.0 * (double)bid + 1.0) - 1.0) * 0.5);
    while ((j + 1) * (j + 2) / 2 <= bid) ++j;
    while (j * (j + 1) / 2 > bid) --j;
    i = bid - j * (j + 1) / 2;
}

// Shared 128x128 MFMA tile: identical code in k_simmax and k_cand ->
// bit-identical fp32 accumulators (MFMA deterministic; per-accumulator
// chain is kt = 0,1,2,3 ascending). Proven direct-load interleave.
__device__ __forceinline__ void gemm128(const short8* __restrict__ fb,
                                        int am0, int bn0, int lane, int wv,
                                        floatx4 (&acc)[4][4])
{
    const int mq = (wv & 1) * 64;
    const int nq = (wv >> 1) * 64;
    const int ta0 = (am0 + mq) >> 4;      // A tile16 base
    const int tb0 = (bn0 + nq) >> 4;      // B tile16 base

    short8 af[4][4];   // [kt][mt]
    #pragma unroll
    for (int mt = 0; mt < 4; mt++)
        #pragma unroll
        for (int kt = 0; kt < 4; kt++)
            af[kt][mt] = fb[((size_t)(ta0 + mt) * 4 + kt) * 64 + lane];

    #pragma unroll
    for (int i = 0; i < 4; i++)
        #pragma unroll
        for (int j = 0; j < 4; j++) acc[i][j] = (floatx4){0.f, 0.f, 0.f, 0.f};

    #pragma unroll
    for (int nt = 0; nt < 4; nt++) {
        #pragma unroll
        for (int kt = 0; kt < 4; kt++) {
            short8 bf8 = fb[((size_t)(tb0 + nt) * 4 + kt) * 64 + lane];
            #pragma unroll
            for (int mt = 0; mt < 4; mt++)
                acc[mt][nt] = __builtin_amdgcn_mfma_f32_16x16x32_bf16(
                    af[kt][mt], bf8, acc[mt][nt], 0, 0, 0);
        }
    }
}

// ---------------------------------------------------------------------------
// Init: deg = 0, ccnt = 0, nbr = self
// ---------------------------------------------------------------------------
__global__ __launch_bounds__(256)
void k_init(int* __restrict__ deg, int* __restrict__ ccnt, int* __restrict__ nbr)
{
    int t = blockIdx.x * 256 + threadIdx.x;
    if (t < NN) { deg[t] = 0; ccnt[t] = 0; }
    if (t < NN * KP1) nbr[t] = t / KP1;
}

// ---------------------------------------------------------------------------
// Preprocess: 8 nodes/block, 128 threads (thread = channel), fp64 math.
// Emits zn64 (optional), z32, zn32, and znbF (fragment-major bf16).
// ---------------------------------------------------------------------------
__global__ __launch_bounds__(128)
void k_pre(const float* __restrict__ x_raw, const float* __restrict__ eps,
           const float* __restrict__ col_logit, const float* __restrict__ type_logit,
           const float* __restrict__ W_enc, const float* __restrict__ b_enc,
           const float* __restrict__ W_mu, const float* __restrict__ b_mu,
           const float* __restrict__ W_lv, const float* __restrict__ b_lv,
           double* __restrict__ zn64, float* __restrict__ z32, float* __restrict__ zn32,
           unsigned short* __restrict__ znbF, int use64)
{
    const int tid = threadIdx.x;
    const int n0  = blockIdx.x * 8;
    __shared__ double xg[8][DD];
    __shared__ double hs[8][CC];
    __shared__ double zs[8][CC];
    __shared__ double part[8][16];
    __shared__ double rs_s[8];
    __shared__ double gcol[DD];

    if (tid < DD) {
        double l = (double)col_logit[tid];
        double s = 1.0 / (1.0 + exp(-l * 0.5));
        gcol[tid] = fmin(fmax(s * 1.2 - 0.1, 0.0), 1.0);
    }
    __syncthreads();

    #pragma unroll
    for (int rpt = 0; rpt < 4; rpt++) {
        int idx = tid + rpt * 128;
        int m = idx >> 6, d = idx & 63;
        xg[m][d] = (double)x_raw[(size_t)(n0 + m) * DD + d] * gcol[d];
    }
    __syncthreads();

    double tg;
    {
        double l = (double)type_logit[0];
        double s = 1.0 / (1.0 + exp(-l * 0.5));
        tg = fmin(fmax(s * 1.2 - 0.1, 0.0), 1.0);
    }

    double h[8];
    #pragma unroll
    for (int m = 0; m < 8; m++) h[m] = (double)b_enc[tid];
    for (int d = 0; d < DD; d++) {
        double w = (double)W_enc[d * CC + tid];
        #pragma unroll
        for (int m = 0; m < 8; m++) h[m] += xg[m][d] * w;
    }
    #pragma unroll
    for (int m = 0; m < 8; m++) hs[m][tid] = h[m] * tg;
    __syncthreads();

    double mu[8], lv[8];
    #pragma unroll
    for (int m = 0; m < 8; m++) { mu[m] = (double)b_mu[tid]; lv[m] = (double)b_lv[tid]; }
    for (int j = 0; j < CC; j++) {
        double wm = (double)W_mu[j * CC + tid];
        double wl = (double)W_lv[j * CC + tid];
        #pragma unroll
        for (int m = 0; m < 8; m++) { double hj = hs[m][j]; mu[m] += hj * wm; lv[m] += hj * wl; }
    }
    #pragma unroll
    for (int m = 0; m < 8; m++) {
        double l = fmin(fmax(lv[m], -10.0), 10.0);
        zs[m][tid] = mu[m] + (double)eps[(size_t)(n0 + m) * CC + tid] * exp(0.5 * l);
    }
    __syncthreads();

    {
        int m = tid >> 4, t = tid & 15;
        double s = 0.0;
        for (int c = t; c < CC; c += 16) { double z = zs[m][c]; s += z * z; }
        part[m][t] = s;
    }
    __syncthreads();
    if (tid < 8) {
        double s = 0.0;
        for (int t = 0; t < 16; t++) s += part[tid][t];
        rs_s[tid] = 1.0 / sqrt(s + 1e-12);
    }
    __syncthreads();

    const int c  = tid;
    const int kt = c >> 5, lk = (c >> 3) & 3, e = c & 7;
    #pragma unroll
    for (int m = 0; m < 8; m++) {
        int n = n0 + m;
        double z  = zs[m][tid];
        double zn = z * rs_s[m];
        size_t o  = (size_t)n * CC + tid;
        if (use64) zn64[o] = zn;
        z32[o]  = (float)z;
        float znf = (float)zn;
        zn32[o] = znf;
        size_t fo = ((size_t)((n >> 4) * 4 + kt) * 64 + lk * 16 + (n & 15)) * 8 + e;
        znbF[fo] = f2bf(znf);
    }
}

// ---------------------------------------------------------------------------
// Pass 1: tile maxes, upper-triangle grid (8256 blocks). Each block emits
// row-maxes AND col-maxes from the same accumulators. Every simmax slot
// written exactly once (diagonal: double-write of identical values, benign).
// ---------------------------------------------------------------------------
__global__ __launch_bounds__(256)
void k_simmax(const unsigned short* __restrict__ znbF, float* __restrict__ simmax)
{
    const int tid  = threadIdx.x;
    const int lane = tid & 63;
    const int wv   = tid >> 6;
    int bx, by;
    tri_coords(blockIdx.x, bx, by);          // bx <= by
    const int am0  = bx * 128;
    const int bn0  = by * 128;
    const int mw   = wv & 1;
    const int nw   = wv >> 1;
    const int mq   = mw * 64;
    const int nq   = nw * 64;
    const int lm   = lane & 15;
    const int lk   = lane >> 4;

    floatx4 acc[4][4];
    gemm128((const short8*)znbF, am0, bn0, lane, wv, acc);

    // Row maxes: max over this wave's 64 cols for each of its 64 rows.
    #pragma unroll
    for (int mt = 0; mt < 4; mt++)
        #pragma unroll
        for (int rg = 0; rg < 4; rg++) {
            int m = mq + mt * 16 + lk * 4 + rg;
            float mx = acc[mt][0][rg];
            #pragma unroll
            for (int nt = 1; nt < 4; nt++) mx = fmaxf(mx, acc[mt][nt][rg]);
            #pragma unroll
            for (int s = 1; s < 16; s <<= 1) mx = fmaxf(mx, __shfl_xor(mx, s));
            if (lm == 0)
                simmax[(size_t)(am0 + m) * NT + (by * 2 + nw)] = mx;
        }

    // Col maxes (transposed view) -> simmax[col][bx*2 + mw].
    #pragma unroll
    for (int nt = 0; nt < 4; nt++) {
        float cmx = acc[0][nt][0];
        #pragma unroll
        for (int mt = 0; mt < 4; mt++)
            #pragma unroll
            for (int rg = 0; rg < 4; rg++) cmx = fmaxf(cmx, acc[mt][nt][rg]);
        cmx = fmaxf(cmx, __shfl_xor(cmx, 16));
        cmx = fmaxf(cmx, __shfl_xor(cmx, 32));
        if (lane < 16) {
            int coll = bn0 + nq + nt * 16 + lm;
            simmax[(size_t)coll * NT + (bx * 2 + mw)] = cmx;
        }
    }
}

// ---------------------------------------------------------------------------
// L[row] = 32nd-largest tile max (covers the acc-top-32; fp64 margin to the
// true top-17 ~1.8e-2 >> bf16-acc noise ~1e-3).
// ---------------------------------------------------------------------------
__global__ __launch_bounds__(256)
void k_thresh(const float* __restrict__ simmax, float* __restrict__ Lrow)
{
    const int r = blockIdx.x;
    const int tid = threadIdx.x;
    __shared__ float smax[NT];
    smax[tid] = simmax[(size_t)r * NT + tid];
    __syncthreads();
    float v = smax[tid];
    int rank = 0;
    for (int j = 0; j < NT; j++) {
        float w = smax[j];
        rank += (w > v || (w == v && j < tid)) ? 1 : 0;
    }
    if (rank == 31) Lrow[r] = v;
}

// ---------------------------------------------------------------------------
// Pass 2: upper-triangle grid, bit-identical acc via shared gemm128. Each
// element checked against L[row] AND, off-diagonal, against L[col].
// ---------------------------------------------------------------------------
__global__ __launch_bounds__(256)
void k_cand(const unsigned short* __restrict__ znbF, const float* __restrict__ Lrow,
            int* __restrict__ ccnt, int* __restrict__ ccol)
{
    __shared__ float LshA[128], LshB[128];
    const int tid  = threadIdx.x;
    const int lane = tid & 63;
    const int wv   = tid >> 6;
    int bx, by;
    tri_coords(blockIdx.x, bx, by);          // bx <= by
    const int am0  = bx * 128;
    const int bn0  = by * 128;
    const int mw   = wv & 1;
    const int nw   = wv >> 1;
    const int mq   = mw * 64;
    const int nq   = nw * 64;
    const int lm   = lane & 15;
    const int lk   = lane >> 4;
    const int diag = (bx == by);

    if (tid < 128) LshA[tid] = Lrow[am0 + tid] - 1e-3f;        // wide margin
    else           LshB[tid - 128] = Lrow[bn0 + tid - 128] - 1e-3f;
    __syncthreads();

    floatx4 acc[4][4];
    gemm128((const short8*)znbF, am0, bn0, lane, wv, acc);

    #pragma unroll
    for (int mt = 0; mt < 4; mt++)
        #pragma unroll
        for (int rg = 0; rg < 4; rg++) {
            int m = mq + mt * 16 + lk * 4 + rg;
            float Lr = LshA[m];
            int row = am0 + m;
            #pragma unroll
            for (int nt = 0; nt < 4; nt++) {
                float v = acc[mt][nt][rg];
                int lcol = nq + nt * 16 + lm;
                if (v >= Lr) {
                    int p = atomicAdd(&ccnt[row], 1);
                    if (p < CAP) ccol[(size_t)row * CAP + p] = bn0 + lcol;
                }
                if (!diag && v >= LshB[lcol]) {
                    int coll = bn0 + lcol;
                    int p = atomicAdd(&ccnt[coll], 1);
                    if (p < CAP) ccol[(size_t)coll * CAP + p] = row;
                }
            }
        }
}

// ---------------------------------------------------------------------------
// Final: fp64 re-rank of all candidates -> exact top-17; emits nbr + deg.
// ---------------------------------------------------------------------------
__global__ __launch_bounds__(256)
void k_topk2(const int* __restrict__ ccnt, const int* __restrict__ ccol,
             const double* __restrict__ zn64, const float* __restrict__ zn32,
             int* __restrict__ nbr, int* __restrict__ deg, int use64)
{
    const int r = blockIdx.x;
    const int tid = threadIdx.x;
    __shared__ double q[CC];
    __shared__ double dv[CAP];
    __shared__ int    cs[CAP];

    int C = ccnt[r]; if (C > CAP) C = CAP;
    if (tid < CC)
        q[tid] = use64 ? zn64[(size_t)r * CC + tid] : (double)zn32[(size_t)r * CC + tid];
    if (tid < C) {
        int cx = ccol[(size_t)r * CAP + tid];
        cs[tid] = ((unsigned)cx < (unsigned)NN) ? cx : r;
    }
    __syncthreads();
    if (tid < C) {
        int cx = cs[tid];
        double s = 0.0;
        if (use64) {
            const double* zr = zn64 + (size_t)cx * CC;
            for (int k = 0; k < CC; k++) s += q[k] * zr[k];
        } else {
            const float* zr = zn32 + (size_t)cx * CC;
            for (int k = 0; k < CC; k++) s += q[k] * (double)zr[k];
        }
        dv[tid] = s;
    }
    __syncthreads();
    if (tid < C) {
        double v = dv[tid]; int ix = cs[tid];
        int rank = 0;
        for (int j = 0; j < C; j++) {
            double w = dv[j];
            rank += (w > v || (w == v && cs[j] < ix)) ? 1 : 0;
        }
        if (rank < KP1) {
            nbr[(size_t)r * KP1 + rank] = ix;
            if (ix != r && (unsigned)ix < (unsigned)NN) atomicAdd(&deg[ix], 1);
        }
    }
}

// ---------------------------------------------------------------------------
// Scan: one block, shuffle-based, 2 barriers.
// ---------------------------------------------------------------------------
__global__ __launch_bounds__(256)
void k_scan(const int* __restrict__ deg, int* __restrict__ rp, int* __restrict__ wp)
{
    const int tid  = threadIdx.x;
    const int lane = tid & 63;
    const int wv   = tid >> 6;
    const int base = tid * 64;

    int v[64];
    int sum = 0;
    #pragma unroll
    for (int i = 0; i < 16; i++) {
        int4 t = *(const int4*)&deg[base + i * 4];
        v[i*4+0] = t.x; v[i*4+1] = t.y; v[i*4+2] = t.z; v[i*4+3] = t.w;
        sum += t.x + t.y + t.z + t.w;
    }

    int inc = sum;
    #pragma unroll
    for (int off2 = 1; off2 < 64; off2 <<= 1) {
        int o = __shfl_up(inc, off2);
        if (lane >= off2) inc += o;
    }

    __shared__ int wtot[4];
    if (lane == 63) wtot[wv] = inc;
    __syncthreads();
    int woff = 0;
    for (int w = 0; w < wv; w++) woff += wtot[w];

    int run = woff + inc - sum;
    #pragma unroll
    for (int i = 0; i < 64; i++) {
        wp[base + i] = run;
        run += v[i];
        rp[base + i + 1] = run;
    }
    if (tid == 0) rp[0] = 0;
}

__global__ __launch_bounds__(256)
void k_fill(const int* __restrict__ nbr, int* __restrict__ wp, int* __restrict__ es)
{
    int e = blockIdx.x * 256 + threadIdx.x;
    if (e >= NN * KP1) return;
    int i = e / KP1;
    int dst = nbr[e];
    if (dst != i && (unsigned)dst < (unsigned)NN) {
        int pos = atomicAdd(&wp[dst], 1);
        if ((unsigned)pos < (unsigned)(NN * KP1)) es[pos] = i;
    }
}

// ---------------------------------------------------------------------------
// Fused SAGE layer 1: mean-gather (CSR) + relu(z@Ws + mean@Wn + b) -> h1.
// 8 nodes/block, 128 threads (thread = channel). Summation order identical
// to the previous k_gather (t ascending) + k_layer (j ascending).
// ---------------------------------------------------------------------------
__global__ __launch_bounds__(128)
void k_sage1(const float* __restrict__ z, const int* __restrict__ rp,
             const int* __restrict__ es,
             const float* __restrict__ Ws, const float* __restrict__ Wn,
             const float* __restrict__ bias, float* __restrict__ out)
{
    __shared__ float as[8][CC], ms[8][CC];
    const int tid = threadIdx.x;
    const int n0 = blockIdx.x * 8;

    #pragma unroll
    for (int m = 0; m < 8; m++) {
        int n = n0 + m;
        as[m][tid] = z[(size_t)n * CC + tid];
        int b = rp[n], e2 = rp[n + 1];
        if (b < 0) b = 0;
        if (e2 > NN * KP1) e2 = NN * KP1;
        float acc = 0.f;
        int cnt = 0;
        for (int t = b; t < e2; t++) {
            int s = es[t];
            if ((unsigned)s < (unsigned)NN) { acc += z[(size_t)s * CC + tid]; cnt++; }
        }
        ms[m][tid] = acc / fmaxf((float)cnt, 1.0f);
    }
    __syncthreads();

    float acc[8];
    #pragma unroll
    for (int m = 0; m < 8; m++) acc[m] = bias[tid];
    for (int j = 0; j < CC; j++) {
        float ws = Ws[j * CC + tid], wn = Wn[j * CC + tid];
        #pragma unroll
        for (int m = 0; m < 8; m++) acc[m] += as[m][j] * ws + ms[m][j] * wn;
    }
    #pragma unroll
    for (int m = 0; m < 8; m++)
        out[(size_t)(n0 + m) * CC + tid] = fmaxf(acc[m], 0.f);
}

// ---------------------------------------------------------------------------
// Fused SAGE layer 2 + head: mean-gather (CSR on h1) + relu(...) -> h2 (LDS)
// -> out = h2 @ W_head + b_head. Same j-ascending order as before.
// ---------------------------------------------------------------------------
__global__ __launch_bounds__(128)
void k_sage2h(const float* __restrict__ h1, const int* __restrict__ rp,
              const int* __restrict__ es,
              const float* __restrict__ Ws, const float* __restrict__ Wn,
              const float* __restrict__ bias,
              const float* __restrict__ Wh, const float* __restrict__ bh,
              float* __restrict__ out)
{
    __shared__ float as[8][CC], ms[8][CC], hs[8][CC];
    const int tid = threadIdx.x;
    const int n0 = blockIdx.x * 8;

    #pragma unroll
    for (int m = 0; m < 8; m++) {
        int n = n0 + m;
        as[m][tid] = h1[(size_t)n * CC + tid];
        int b = rp[n], e2 = rp[n + 1];
        if (b < 0) b = 0;
        if (e2 > NN * KP1) e2 = NN * KP1;
        float acc = 0.f;
        int cnt = 0;
        for (int t = b; t < e2; t++) {
            int s = es[t];
            if ((unsigned)s < (unsigned)NN) { acc += h1[(size_t)s * CC + tid]; cnt++; }
        }
        ms[m][tid] = acc / fmaxf((float)cnt, 1.0f);
    }
    __syncthreads();

    float acc[8];
    #pragma unroll
    for (int m = 0; m < 8; m++) acc[m] = bias[tid];
    for (int j = 0; j < CC; j++) {
        float ws = Ws[j * CC + tid], wn = Wn[j * CC + tid];
        #pragma unroll
        for (int m = 0; m < 8; m++) acc[m] += as[m][j] * ws + ms[m][j] * wn;
    }
    #pragma unroll
    for (int m = 0; m < 8; m++) hs[m][tid] = fmaxf(acc[m], 0.f);
    __syncthreads();

    float acc2[8];
    #pragma unroll
    for (int m = 0; m < 8; m++) acc2[m] = bh[tid];
    for (int j = 0; j < CC; j++) {
        float w = Wh[j * OO + tid];
        #pragma unroll
        for (int m = 0; m < 8; m++) acc2[m] += hs[m][j] * w;
    }
    #pragma unroll
    for (int m = 0; m < 8; m++)
        out[(size_t)(n0 + m) * OO + tid] = acc2[m];
}

// ---------------------------------------------------------------------------
extern "C" void kernel_launch(void* const* d_in, const int* in_sizes, int n_in,
                              void* d_out, int out_size, void* d_ws, size_t ws_size,
                              hipStream_t stream)
{
    const float* x_raw      = (const float*)d_in[0];
    const float* eps        = (const float*)d_in[1];
    const float* col_logit  = (const float*)d_in[2];
    const float* type_logit = (const float*)d_in[3];
    const float* W_enc      = (const float*)d_in[4];
    const float* b_enc      = (const float*)d_in[5];
    const float* W_mu       = (const float*)d_in[6];
    const float* b_mu       = (const float*)d_in[7];
    const float* W_lv       = (const float*)d_in[8];
    const float* b_lv       = (const float*)d_in[9];
    const float* W_self1    = (const float*)d_in[10];
    const float* W_nbr1     = (const float*)d_in[11];
    const float* b1         = (const float*)d_in[12];
    const float* W_self2    = (const float*)d_in[13];
    const float* W_nbr2     = (const float*)d_in[14];
    const float* b2         = (const float*)d_in[15];
    const float* W_head     = (const float*)d_in[16];
    const float* b_head     = (const float*)d_in[17];
    float* out              = (float*)d_out;

    char* base = (char*)d_ws;
    size_t off = 0;
    auto alloc = [&](size_t bytes) { size_t o = off; off = (off + bytes + 255) & ~(size_t)255; return o; };

    const size_t MAT  = (size_t)NN * CC * 4;   // 8.39 MB

    float* z32    = (float*)(base + alloc(MAT));
    float* zn32   = (float*)(base + alloc(MAT));
    float* h1     = (float*)(base + alloc(MAT));
    unsigned short* znbF = (unsigned short*)(base + alloc((size_t)NN * CC * 2)); // 4.2 MB
    float* simmax = (float*)(base + alloc((size_t)NN * NT * 4));               // 16.8 MB
    float* Lrow   = (float*)(base + alloc((size_t)NN * 4));
    int*   ccnt   = (int*)(base + alloc((size_t)NN * 4));
    int*   ccol   = (int*)(base + alloc((size_t)NN * CAP * 4));                // 16.8 MB
    int*   nbr    = (int*)(base + alloc((size_t)NN * KP1 * 4));
    int*   deg    = (int*)(base + alloc((size_t)NN * 4));
    int*   rp     = (int*)(base + alloc((size_t)(NN + 1) * 4));
    int*   wp     = (int*)(base + alloc((size_t)NN * 4));
    int*   es     = (int*)(base + alloc((size_t)NN * KP1 * 4));
    size_t fixed = off;   // ~70 MB

    int use64 = (ws_size >= fixed + (size_t)NN * CC * 8 + 4096) ? 1 : 0;
    double* zn64 = nullptr;
    if (use64) zn64 = (double*)(base + alloc((size_t)NN * CC * 8));            // 16.8 MB

    k_init<<<(NN * KP1 + 255) / 256, 256, 0, stream>>>(deg, ccnt, nbr);

    k_pre<<<NN / 8, 128, 0, stream>>>(x_raw, eps, col_logit, type_logit,
                                      W_enc, b_enc, W_mu, b_mu, W_lv, b_lv,
                                      zn64, z32, zn32, znbF, use64);

    const int NTRI = (128 * 129) / 2;          // 8256 upper-triangle blocks
    k_simmax<<<NTRI, 256, 0, stream>>>(znbF, simmax);
    k_thresh<<<NN, 256, 0, stream>>>(simmax, Lrow);
    k_cand<<<NTRI, 256, 0, stream>>>(znbF, Lrow, ccnt, ccol);
    k_topk2<<<NN, 256, 0, stream>>>(ccnt, ccol, zn64, zn32, nbr, deg, use64);

    k_scan<<<1, 256, 0, stream>>>(deg, rp, wp);
    int eb = (NN * KP1 + 255) / 256;
    k_fill<<<eb, 256, 0, stream>>>(nbr, wp, es);

    k_sage1<<<NN / 8, 128, 0, stream>>>(z32, rp, es, W_self1, W_nbr1, b1, h1);
    k_sage2h<<<NN / 8, 128, 0, stream>>>(h1, rp, es, W_self2, W_nbr2, b2,
                                         W_head, b_head, out);

    (void)in_sizes; (void)n_in; (void)out_size;
}

// Round 8
// 790.992 us; speedup vs baseline: 1.0129x; 1.0129x over previous
//
#include <hip/hip_runtime.h>
#include <hip/hip_bf16.h>
#include <math.h>

constexpr int NN  = 16384;
constexpr int DD  = 64;
constexpr int CC  = 128;
constexpr int OO  = 128;
constexpr int KP1 = 17;
constexpr int NT  = 256;             // 64-col tiles per row
constexpr int CAP = 256;             // candidate cap per row

typedef __attribute__((ext_vector_type(8))) short short8;
typedef __attribute__((ext_vector_type(4))) float floatx4;

__device__ __forceinline__ float bf2f(unsigned short u) {
    union { unsigned u; float f; } c; c.u = ((unsigned)u) << 16; return c.f;
}
__device__ __forceinline__ unsigned short f2bf(float f) {
    union { float f; unsigned u; } c; c.f = f;
    unsigned b = c.u;
    return (unsigned short)((b + 0x7FFFu + ((b >> 16) & 1u)) >> 16);
}

// ---------------------------------------------------------------------------
// znbF: fragment-major bf16 layout. For node n, channel c:
//   tile t = n>>4, lm = n&15, kt = c>>5, lk = (c>>3)&3, e = c&7, lane = lk*16+lm
//   znbF[ ((t*4 + kt)*64 + lane)*8 + e ]
//
// GEMM notes (rounds 1-6 post-mortems, MI355X):
//  - LDS staging (any depth) and all-upfront loads LOSE to the simple
//    interleaved direct-load schedule (latency-bound, but best measured).
//  - XCD swizzle: 14x FETCH blowup. Natural dispatch order only.
//  - Symmetry sim = zn.zn^T: triangle grid; acc serves both (r,c) and (c,r);
//    bit-identical fp32. Verified R6: 895 -> 793 us, absmax unchanged.
//  - R7: supertile 128x256 -- A-fragments register-resident, stream two
//    B-panels (by = 2s, 2s+1; ragged diagonal skips by < bx). Cuts fragment
//    traffic 25% and lengthens the per-wave independent-load window.
//    launch_bounds(256,2) guards the 1-wave VGPR cliff.
// ---------------------------------------------------------------------------

// Supertile decode: bid -> (bx, s); per s, bx in [0, 2s+1]. Prefix s^2+s.
__device__ __forceinline__ void super_coords(int bid, int& bx, int& s) {
    s = (int)((sqrt(4.0 * (double)bid + 1.0) - 1.0) * 0.5);
    while (s * s + s > bid) --s;
    while ((s + 1) * (s + 1) + (s + 1) <= bid) ++s;
    bx = bid - (s * s + s);
}

// A-fragment load: 16 x 1KB, values identical to previous rounds.
__device__ __forceinline__ void load_af(const short8* __restrict__ fb,
                                        int am0, int lane, int wv,
                                        short8 (&af)[4][4])
{
    const int mq  = (wv & 1) * 64;
    const int ta0 = (am0 + mq) >> 4;
    #pragma unroll
    for (int mt = 0; mt < 4; mt++)
        #pragma unroll
        for (int kt = 0; kt < 4; kt++)
            af[kt][mt] = fb[((size_t)(ta0 + mt) * 4 + kt) * 64 + lane];
}

// B-stream + MFMA for one 128x128 tile. Per-accumulator chain: kt = 0,1,2,3
// ascending -> identical inline code in k_simmax/k_cand -> bit-identical acc.
__device__ __forceinline__ void gemm_b(const short8* __restrict__ fb,
                                       int bn0, int lane, int wv,
                                       const short8 (&af)[4][4],
                                       floatx4 (&acc)[4][4])
{
    const int nq  = (wv >> 1) * 64;
    const int tb0 = (bn0 + nq) >> 4;

    #pragma unroll
    for (int i = 0; i < 4; i++)
        #pragma unroll
        for (int j = 0; j < 4; j++) acc[i][j] = (floatx4){0.f, 0.f, 0.f, 0.f};

    #pragma unroll
    for (int nt = 0; nt < 4; nt++) {
        #pragma unroll
        for (int kt = 0; kt < 4; kt++) {
            short8 bf8 = fb[((size_t)(tb0 + nt) * 4 + kt) * 64 + lane];
            #pragma unroll
            for (int mt = 0; mt < 4; mt++)
                acc[mt][nt] = __builtin_amdgcn_mfma_f32_16x16x32_bf16(
                    af[kt][mt], bf8, acc[mt][nt], 0, 0, 0);
        }
    }
}

// ---------------------------------------------------------------------------
// Init: deg = 0, ccnt = 0, nbr = self
// ---------------------------------------------------------------------------
__global__ __launch_bounds__(256)
void k_init(int* __restrict__ deg, int* __restrict__ ccnt, int* __restrict__ nbr)
{
    int t = blockIdx.x * 256 + threadIdx.x;
    if (t < NN) { deg[t] = 0; ccnt[t] = 0; }
    if (t < NN * KP1) nbr[t] = t / KP1;
}

// ---------------------------------------------------------------------------
// Preprocess: 8 nodes/block, 128 threads (thread = channel), fp64 math.
// Emits zn64 (optional), z32, zn32, and znbF (fragment-major bf16).
// ---------------------------------------------------------------------------
__global__ __launch_bounds__(128)
void k_pre(const float* __restrict__ x_raw, const float* __restrict__ eps,
           const float* __restrict__ col_logit, const float* __restrict__ type_logit,
           const float* __restrict__ W_enc, const float* __restrict__ b_enc,
           const float* __restrict__ W_mu, const float* __restrict__ b_mu,
           const float* __restrict__ W_lv, const float* __restrict__ b_lv,
           double* __restrict__ zn64, float* __restrict__ z32, float* __restrict__ zn32,
           unsigned short* __restrict__ znbF, int use64)
{
    const int tid = threadIdx.x;
    const int n0  = blockIdx.x * 8;
    __shared__ double xg[8][DD];
    __shared__ double hs[8][CC];
    __shared__ double zs[8][CC];
    __shared__ double part[8][16];
    __shared__ double rs_s[8];
    __shared__ double gcol[DD];

    if (tid < DD) {
        double l = (double)col_logit[tid];
        double s = 1.0 / (1.0 + exp(-l * 0.5));
        gcol[tid] = fmin(fmax(s * 1.2 - 0.1, 0.0), 1.0);
    }
    __syncthreads();

    #pragma unroll
    for (int rpt = 0; rpt < 4; rpt++) {
        int idx = tid + rpt * 128;
        int m = idx >> 6, d = idx & 63;
        xg[m][d] = (double)x_raw[(size_t)(n0 + m) * DD + d] * gcol[d];
    }
    __syncthreads();

    double tg;
    {
        double l = (double)type_logit[0];
        double s = 1.0 / (1.0 + exp(-l * 0.5));
        tg = fmin(fmax(s * 1.2 - 0.1, 0.0), 1.0);
    }

    double h[8];
    #pragma unroll
    for (int m = 0; m < 8; m++) h[m] = (double)b_enc[tid];
    for (int d = 0; d < DD; d++) {
        double w = (double)W_enc[d * CC + tid];
        #pragma unroll
        for (int m = 0; m < 8; m++) h[m] += xg[m][d] * w;
    }
    #pragma unroll
    for (int m = 0; m < 8; m++) hs[m][tid] = h[m] * tg;
    __syncthreads();

    double mu[8], lv[8];
    #pragma unroll
    for (int m = 0; m < 8; m++) { mu[m] = (double)b_mu[tid]; lv[m] = (double)b_lv[tid]; }
    for (int j = 0; j < CC; j++) {
        double wm = (double)W_mu[j * CC + tid];
        double wl = (double)W_lv[j * CC + tid];
        #pragma unroll
        for (int m = 0; m < 8; m++) { double hj = hs[m][j]; mu[m] += hj * wm; lv[m] += hj * wl; }
    }
    #pragma unroll
    for (int m = 0; m < 8; m++) {
        double l = fmin(fmax(lv[m], -10.0), 10.0);
        zs[m][tid] = mu[m] + (double)eps[(size_t)(n0 + m) * CC + tid] * exp(0.5 * l);
    }
    __syncthreads();

    {
        int m = tid >> 4, t = tid & 15;
        double s = 0.0;
        for (int c = t; c < CC; c += 16) { double z = zs[m][c]; s += z * z; }
        part[m][t] = s;
    }
    __syncthreads();
    if (tid < 8) {
        double s = 0.0;
        for (int t = 0; t < 16; t++) s += part[tid][t];
        rs_s[tid] = 1.0 / sqrt(s + 1e-12);
    }
    __syncthreads();

    const int c  = tid;
    const int kt = c >> 5, lk = (c >> 3) & 3, e = c & 7;
    #pragma unroll
    for (int m = 0; m < 8; m++) {
        int n = n0 + m;
        double z  = zs[m][tid];
        double zn = z * rs_s[m];
        size_t o  = (size_t)n * CC + tid;
        if (use64) zn64[o] = zn;
        z32[o]  = (float)z;
        float znf = (float)zn;
        zn32[o] = znf;
        size_t fo = ((size_t)((n >> 4) * 4 + kt) * 64 + lk * 16 + (n & 15)) * 8 + e;
        znbF[fo] = f2bf(znf);
    }
}

// ---------------------------------------------------------------------------
// Pass 1: tile maxes, supertile grid (4160 blocks). A-frags loaded once,
// two B-panels streamed (by = 2s, 2s+1; skip by < bx). Row maxes AND col
// maxes emitted per tile from the same accumulators.
// ---------------------------------------------------------------------------
__global__ __launch_bounds__(256, 2)
void k_simmax(const unsigned short* __restrict__ znbF, float* __restrict__ simmax)
{
    const short8* fb = (const short8*)znbF;
    const int tid  = threadIdx.x;
    const int lane = tid & 63;
    const int wv   = tid >> 6;
    int bx, s;
    super_coords(blockIdx.x, bx, s);
    const int am0  = bx * 128;
    const int mw   = wv & 1;
    const int nw   = wv >> 1;
    const int mq   = mw * 64;
    const int nq   = nw * 64;
    const int lm   = lane & 15;
    const int lk   = lane >> 4;

    short8 af[4][4];
    load_af(fb, am0, lane, wv, af);

    #pragma unroll
    for (int h = 0; h < 2; h++) {
        const int by = 2 * s + h;
        if (by < bx) continue;
        const int bn0 = by * 128;

        floatx4 acc[4][4];
        gemm_b(fb, bn0, lane, wv, af, acc);

        // Row maxes.
        #pragma unroll
        for (int mt = 0; mt < 4; mt++)
            #pragma unroll
            for (int rg = 0; rg < 4; rg++) {
                int m = mq + mt * 16 + lk * 4 + rg;
                float mx = acc[mt][0][rg];
                #pragma unroll
                for (int nt = 1; nt < 4; nt++) mx = fmaxf(mx, acc[mt][nt][rg]);
                #pragma unroll
                for (int ss = 1; ss < 16; ss <<= 1) mx = fmaxf(mx, __shfl_xor(mx, ss));
                if (lm == 0)
                    simmax[(size_t)(am0 + m) * NT + (by * 2 + nw)] = mx;
            }

        // Col maxes (transposed view) -> simmax[col][bx*2 + mw].
        #pragma unroll
        for (int nt = 0; nt < 4; nt++) {
            float cmx = acc[0][nt][0];
            #pragma unroll
            for (int mt = 0; mt < 4; mt++)
                #pragma unroll
                for (int rg = 0; rg < 4; rg++) cmx = fmaxf(cmx, acc[mt][nt][rg]);
            cmx = fmaxf(cmx, __shfl_xor(cmx, 16));
            cmx = fmaxf(cmx, __shfl_xor(cmx, 32));
            if (lane < 16) {
                int coll = bn0 + nq + nt * 16 + lm;
                simmax[(size_t)coll * NT + (bx * 2 + mw)] = cmx;
            }
        }
    }
}

// ---------------------------------------------------------------------------
// L[row] = 32nd-largest tile max (covers the acc-top-32; fp64 margin to the
// true top-17 ~1.8e-2 >> bf16-acc noise ~1e-3).
// ---------------------------------------------------------------------------
__global__ __launch_bounds__(256)
void k_thresh(const float* __restrict__ simmax, float* __restrict__ Lrow)
{
    const int r = blockIdx.x;
    const int tid = threadIdx.x;
    __shared__ float smax[NT];
    smax[tid] = simmax[(size_t)r * NT + tid];
    __syncthreads();
    float v = smax[tid];
    int rank = 0;
    for (int j = 0; j < NT; j++) {
        float w = smax[j];
        rank += (w > v || (w == v && j < tid)) ? 1 : 0;
    }
    if (rank == 31) Lrow[r] = v;
}

// ---------------------------------------------------------------------------
// Pass 2: supertile grid, bit-identical acc (same load_af/gemm_b). Each
// element checked against L[row] AND, off-diagonal, against L[col].
// ---------------------------------------------------------------------------
__global__ __launch_bounds__(256, 2)
void k_cand(const unsigned short* __restrict__ znbF, const float* __restrict__ Lrow,
            int* __restrict__ ccnt, int* __restrict__ ccol)
{
    __shared__ float LshA[128], LshB[2][128];
    const short8* fb = (const short8*)znbF;
    const int tid  = threadIdx.x;
    const int lane = tid & 63;
    const int wv   = tid >> 6;
    int bx, s;
    super_coords(blockIdx.x, bx, s);
    const int am0  = bx * 128;
    const int mw   = wv & 1;
    const int nw   = wv >> 1;
    const int mq   = mw * 64;
    const int nq   = nw * 64;
    const int lm   = lane & 15;
    const int lk   = lane >> 4;

    if (tid < 128) LshA[tid] = Lrow[am0 + tid] - 1e-3f;        // wide margin
    else           LshB[0][tid - 128] = Lrow[(2 * s) * 128 + (tid - 128)] - 1e-3f;
    if (tid < 128) LshB[1][tid] = Lrow[(2 * s + 1) * 128 + tid] - 1e-3f;
    __syncthreads();

    short8 af[4][4];
    load_af(fb, am0, lane, wv, af);

    #pragma unroll
    for (int h = 0; h < 2; h++) {
        const int by = 2 * s + h;
        if (by < bx) continue;
        const int bn0 = by * 128;
        const int diag = (bx == by);

        floatx4 acc[4][4];
        gemm_b(fb, bn0, lane, wv, af, acc);

        #pragma unroll
        for (int mt = 0; mt < 4; mt++)
            #pragma unroll
            for (int rg = 0; rg < 4; rg++) {
                int m = mq + mt * 16 + lk * 4 + rg;
                float Lr = LshA[m];
                int row = am0 + m;
                #pragma unroll
                for (int nt = 0; nt < 4; nt++) {
                    float v = acc[mt][nt][rg];
                    int lcol = nq + nt * 16 + lm;
                    if (v >= Lr) {
                        int p = atomicAdd(&ccnt[row], 1);
                        if (p < CAP) ccol[(size_t)row * CAP + p] = bn0 + lcol;
                    }
                    if (!diag && v >= LshB[h][lcol]) {
                        int coll = bn0 + lcol;
                        int p = atomicAdd(&ccnt[coll], 1);
                        if (p < CAP) ccol[(size_t)coll * CAP + p] = row;
                    }
                }
            }
    }
}

// ---------------------------------------------------------------------------
// Final: fp64 re-rank of all candidates -> exact top-17; emits nbr + deg.
// Gather vectorized to double2/float4 with explicitly sequenced adds ->
// bit-identical dv vs the scalar k-ascending loop.
// ---------------------------------------------------------------------------
__global__ __launch_bounds__(256)
void k_topk2(const int* __restrict__ ccnt, const int* __restrict__ ccol,
             const double* __restrict__ zn64, const float* __restrict__ zn32,
             int* __restrict__ nbr, int* __restrict__ deg, int use64)
{
    const int r = blockIdx.x;
    const int tid = threadIdx.x;
    __shared__ double q[CC];
    __shared__ double dv[CAP];
    __shared__ int    cs[CAP];

    int C = ccnt[r]; if (C > CAP) C = CAP;
    if (tid < CC)
        q[tid] = use64 ? zn64[(size_t)r * CC + tid] : (double)zn32[(size_t)r * CC + tid];
    if (tid < C) {
        int cx = ccol[(size_t)r * CAP + tid];
        cs[tid] = ((unsigned)cx < (unsigned)NN) ? cx : r;
    }
    __syncthreads();
    if (tid < C) {
        int cx = cs[tid];
        double s = 0.0;
        if (use64) {
            const double2* zr2 = (const double2*)(zn64 + (size_t)cx * CC);
            #pragma unroll 4
            for (int k = 0; k < CC / 2; k++) {
                double2 v = zr2[k];
                s += q[2 * k]     * v.x;
                s += q[2 * k + 1] * v.y;
            }
        } else {
            const float4* zr4 = (const float4*)(zn32 + (size_t)cx * CC);
            #pragma unroll 4
            for (int k = 0; k < CC / 4; k++) {
                float4 v = zr4[k];
                s += q[4 * k]     * (double)v.x;
                s += q[4 * k + 1] * (double)v.y;
                s += q[4 * k + 2] * (double)v.z;
                s += q[4 * k + 3] * (double)v.w;
            }
        }
        dv[tid] = s;
    }
    __syncthreads();
    if (tid < C) {
        double v = dv[tid]; int ix = cs[tid];
        int rank = 0;
        for (int j = 0; j < C; j++) {
            double w = dv[j];
            rank += (w > v || (w == v && cs[j] < ix)) ? 1 : 0;
        }
        if (rank < KP1) {
            nbr[(size_t)r * KP1 + rank] = ix;
            if (ix != r && (unsigned)ix < (unsigned)NN) atomicAdd(&deg[ix], 1);
        }
    }
}

// ---------------------------------------------------------------------------
// Scan: one block, shuffle-based, 2 barriers.
// ---------------------------------------------------------------------------
__global__ __launch_bounds__(256)
void k_scan(const int* __restrict__ deg, int* __restrict__ rp, int* __restrict__ wp)
{
    const int tid  = threadIdx.x;
    const int lane = tid & 63;
    const int wv   = tid >> 6;
    const int base = tid * 64;

    int v[64];
    int sum = 0;
    #pragma unroll
    for (int i = 0; i < 16; i++) {
        int4 t = *(const int4*)&deg[base + i * 4];
        v[i*4+0] = t.x; v[i*4+1] = t.y; v[i*4+2] = t.z; v[i*4+3] = t.w;
        sum += t.x + t.y + t.z + t.w;
    }

    int inc = sum;
    #pragma unroll
    for (int off2 = 1; off2 < 64; off2 <<= 1) {
        int o = __shfl_up(inc, off2);
        if (lane >= off2) inc += o;
    }

    __shared__ int wtot[4];
    if (lane == 63) wtot[wv] = inc;
    __syncthreads();
    int woff = 0;
    for (int w = 0; w < wv; w++) woff += wtot[w];

    int run = woff + inc - sum;
    #pragma unroll
    for (int i = 0; i < 64; i++) {
        wp[base + i] = run;
        run += v[i];
        rp[base + i + 1] = run;
    }
    if (tid == 0) rp[0] = 0;
}

__global__ __launch_bounds__(256)
void k_fill(const int* __restrict__ nbr, int* __restrict__ wp, int* __restrict__ es)
{
    int e = blockIdx.x * 256 + threadIdx.x;
    if (e >= NN * KP1) return;
    int i = e / KP1;
    int dst = nbr[e];
    if (dst != i && (unsigned)dst < (unsigned)NN) {
        int pos = atomicAdd(&wp[dst], 1);
        if ((unsigned)pos < (unsigned)(NN * KP1)) es[pos] = i;
    }
}

// ---------------------------------------------------------------------------
// Fused SAGE layer 1: mean-gather (CSR) + relu(z@Ws + mean@Wn + b) -> h1.
// ---------------------------------------------------------------------------
__global__ __launch_bounds__(128)
void k_sage1(const float* __restrict__ z, const int* __restrict__ rp,
             const int* __restrict__ es,
             const float* __restrict__ Ws, const float* __restrict__ Wn,
             const float* __restrict__ bias, float* __restrict__ out)
{
    __shared__ float as[8][CC], ms[8][CC];
    const int tid = threadIdx.x;
    const int n0 = blockIdx.x * 8;

    #pragma unroll
    for (int m = 0; m < 8; m++) {
        int n = n0 + m;
        as[m][tid] = z[(size_t)n * CC + tid];
        int b = rp[n], e2 = rp[n + 1];
        if (b < 0) b = 0;
        if (e2 > NN * KP1) e2 = NN * KP1;
        float acc = 0.f;
        int cnt = 0;
        for (int t = b; t < e2; t++) {
            int s = es[t];
            if ((unsigned)s < (unsigned)NN) { acc += z[(size_t)s * CC + tid]; cnt++; }
        }
        ms[m][tid] = acc / fmaxf((float)cnt, 1.0f);
    }
    __syncthreads();

    float acc[8];
    #pragma unroll
    for (int m = 0; m < 8; m++) acc[m] = bias[tid];
    for (int j = 0; j < CC; j++) {
        float ws = Ws[j * CC + tid], wn = Wn[j * CC + tid];
        #pragma unroll
        for (int m = 0; m < 8; m++) acc[m] += as[m][j] * ws + ms[m][j] * wn;
    }
    #pragma unroll
    for (int m = 0; m < 8; m++)
        out[(size_t)(n0 + m) * CC + tid] = fmaxf(acc[m], 0.f);
}

// ---------------------------------------------------------------------------
// Fused SAGE layer 2 + head: mean-gather + relu(...) -> h2 (LDS) -> head.
// ---------------------------------------------------------------------------
__global__ __launch_bounds__(128)
void k_sage2h(const float* __restrict__ h1, const int* __restrict__ rp,
              const int* __restrict__ es,
              const float* __restrict__ Ws, const float* __restrict__ Wn,
              const float* __restrict__ bias,
              const float* __restrict__ Wh, const float* __restrict__ bh,
              float* __restrict__ out)
{
    __shared__ float as[8][CC], ms[8][CC], hs[8][CC];
    const int tid = threadIdx.x;
    const int n0 = blockIdx.x * 8;

    #pragma unroll
    for (int m = 0; m < 8; m++) {
        int n = n0 + m;
        as[m][tid] = h1[(size_t)n * CC + tid];
        int b = rp[n], e2 = rp[n + 1];
        if (b < 0) b = 0;
        if (e2 > NN * KP1) e2 = NN * KP1;
        float acc = 0.f;
        int cnt = 0;
        for (int t = b; t < e2; t++) {
            int s = es[t];
            if ((unsigned)s < (unsigned)NN) { acc += h1[(size_t)s * CC + tid]; cnt++; }
        }
        ms[m][tid] = acc / fmaxf((float)cnt, 1.0f);
    }
    __syncthreads();

    float acc[8];
    #pragma unroll
    for (int m = 0; m < 8; m++) acc[m] = bias[tid];
    for (int j = 0; j < CC; j++) {
        float ws = Ws[j * CC + tid], wn = Wn[j * CC + tid];
        #pragma unroll
        for (int m = 0; m < 8; m++) acc[m] += as[m][j] * ws + ms[m][j] * wn;
    }
    #pragma unroll
    for (int m = 0; m < 8; m++) hs[m][tid] = fmaxf(acc[m], 0.f);
    __syncthreads();

    float acc2[8];
    #pragma unroll
    for (int m = 0; m < 8; m++) acc2[m] = bh[tid];
    for (int j = 0; j < CC; j++) {
        float w = Wh[j * OO + tid];
        #pragma unroll
        for (int m = 0; m < 8; m++) acc2[m] += hs[m][j] * w;
    }
    #pragma unroll
    for (int m = 0; m < 8; m++)
        out[(size_t)(n0 + m) * OO + tid] = acc2[m];
}

// ---------------------------------------------------------------------------
extern "C" void kernel_launch(void* const* d_in, const int* in_sizes, int n_in,
                              void* d_out, int out_size, void* d_ws, size_t ws_size,
                              hipStream_t stream)
{
    const float* x_raw      = (const float*)d_in[0];
    const float* eps        = (const float*)d_in[1];
    const float* col_logit  = (const float*)d_in[2];
    const float* type_logit = (const float*)d_in[3];
    const float* W_enc      = (const float*)d_in[4];
    const float* b_enc      = (const float*)d_in[5];
    const float* W_mu       = (const float*)d_in[6];
    const float* b_mu       = (const float*)d_in[7];
    const float* W_lv       = (const float*)d_in[8];
    const float* b_lv       = (const float*)d_in[9];
    const float* W_self1    = (const float*)d_in[10];
    const float* W_nbr1     = (const float*)d_in[11];
    const float* b1         = (const float*)d_in[12];
    const float* W_self2    = (const float*)d_in[13];
    const float* W_nbr2     = (const float*)d_in[14];
    const float* b2         = (const float*)d_in[15];
    const float* W_head     = (const float*)d_in[16];
    const float* b_head     = (const float*)d_in[17];
    float* out              = (float*)d_out;

    char* base = (char*)d_ws;
    size_t off = 0;
    auto alloc = [&](size_t bytes) { size_t o = off; off = (off + bytes + 255) & ~(size_t)255; return o; };

    const size_t MAT  = (size_t)NN * CC * 4;   // 8.39 MB

    float* z32    = (float*)(base + alloc(MAT));
    float* zn32   = (float*)(base + alloc(MAT));
    float* h1     = (float*)(base + alloc(MAT));
    unsigned short* znbF = (unsigned short*)(base + alloc((size_t)NN * CC * 2)); // 4.2 MB
    float* simmax = (float*)(base + alloc((size_t)NN * NT * 4));               // 16.8 MB
    float* Lrow   = (float*)(base + alloc((size_t)NN * 4));
    int*   ccnt   = (int*)(base + alloc((size_t)NN * 4));
    int*   ccol   = (int*)(base + alloc((size_t)NN * CAP * 4));                // 16.8 MB
    int*   nbr    = (int*)(base + alloc((size_t)NN * KP1 * 4));
    int*   deg    = (int*)(base + alloc((size_t)NN * 4));
    int*   rp     = (int*)(base + alloc((size_t)(NN + 1) * 4));
    int*   wp     = (int*)(base + alloc((size_t)NN * 4));
    int*   es     = (int*)(base + alloc((size_t)NN * KP1 * 4));
    size_t fixed = off;   // ~70 MB

    int use64 = (ws_size >= fixed + (size_t)NN * CC * 8 + 4096) ? 1 : 0;
    double* zn64 = nullptr;
    if (use64) zn64 = (double*)(base + alloc((size_t)NN * CC * 8));            // 16.8 MB

    k_init<<<(NN * KP1 + 255) / 256, 256, 0, stream>>>(deg, ccnt, nbr);

    k_pre<<<NN / 8, 128, 0, stream>>>(x_raw, eps, col_logit, type_logit,
                                      W_enc, b_enc, W_mu, b_mu, W_lv, b_lv,
                                      zn64, z32, zn32, znbF, use64);

    const int NSUP = 64 * 64 + 64;             // 4160 supertile blocks
    k_simmax<<<NSUP, 256, 0, stream>>>(znbF, simmax);
    k_thresh<<<NN, 256, 0, stream>>>(simmax, Lrow);
    k_cand<<<NSUP, 256, 0, stream>>>(znbF, Lrow, ccnt, ccol);
    k_topk2<<<NN, 256, 0, stream>>>(ccnt, ccol, zn64, zn32, nbr, deg, use64);

    k_scan<<<1, 256, 0, stream>>>(deg, rp, wp);
    int eb = (NN * KP1 + 255) / 256;
    k_fill<<<eb, 256, 0, stream>>>(nbr, wp, es);

    k_sage1<<<NN / 8, 128, 0, stream>>>(z32, rp, es, W_self1, W_nbr1, b1, h1);
    k_sage2h<<<NN / 8, 128, 0, stream>>>(h1, rp, es, W_self2, W_nbr2, b2,
                                         W_head, b_head, out);

    (void)in_sizes; (void)n_in; (void)out_size;
}